// Round 1
// baseline (1874.012 us; speedup 1.0000x reference)
//
#include <hip/hip_runtime.h>
#include <math.h>

// LSTM: B=256, T=2048, D=64, H=64, OUT=8. fp32 throughout.
// One block per batch row (256 blocks == 256 CUs). 256 threads: thread g
// computes gate output g (wave0=i, wave1=f, wave2=g/tanh, wave3=o).
// Weight rows live in registers (128 VGPR/thread); h broadcast via LDS.

#define Hh  64
#define Tt  2048
#define Dd  64
#define Bb  256
#define OUTN 8

__global__ __launch_bounds__(256, 1)
void lstm_fused_kernel(const float* __restrict__ x,
                       const float* __restrict__ w_ih,
                       const float* __restrict__ w_hh,
                       const float* __restrict__ b_ih,
                       const float* __restrict__ b_hh,
                       const float* __restrict__ fc_w,
                       const float* __restrict__ fc_b,
                       float* __restrict__ out)
{
    __shared__ float h_s[Hh];         // hidden state broadcast buffer
    __shared__ float x_s[2][Dd];      // double-buffered x_t
    __shared__ float gate_s[3 * Hh];  // activated i, f, g

    const int tid  = threadIdx.x;     // 0..255 == gate index
    const int b    = blockIdx.x;      // batch row
    const int wave = tid >> 6;        // 0:i 1:f 2:g 3:o
    const int lane = tid & 63;

    // --- load this thread's weight rows into registers (one-time) ---
    float wih[Dd], whh[Hh];
    {
        const float4* p = (const float4*)(w_ih + (size_t)tid * Dd);
        #pragma unroll
        for (int k = 0; k < Dd / 4; ++k) {
            float4 v = p[k];
            wih[4*k+0] = v.x; wih[4*k+1] = v.y; wih[4*k+2] = v.z; wih[4*k+3] = v.w;
        }
        const float4* q = (const float4*)(w_hh + (size_t)tid * Hh);
        #pragma unroll
        for (int k = 0; k < Hh / 4; ++k) {
            float4 v = q[k];
            whh[4*k+0] = v.x; whh[4*k+1] = v.y; whh[4*k+2] = v.z; whh[4*k+3] = v.w;
        }
    }
    const float bias = b_ih[tid] + b_hh[tid];

    // --- init state ---
    const float* xb = x + (size_t)b * Tt * Dd;
    if (tid < Hh) h_s[tid] = 0.0f;
    if (tid < Dd) x_s[0][tid] = xb[tid];
    float c = 0.0f;                   // c[lane], valid in wave 3
    __syncthreads();

    for (int t = 0; t < Tt; ++t) {
        // prefetch x[t+1] (register, stored to LDS just before barrier A)
        float xn = 0.0f;
        if (tid < Dd) {
            int tn = (t + 1 < Tt) ? (t + 1) : t;
            xn = xb[(size_t)tn * Dd + tid];
        }

        // gate pre-activation: bias + w_ih[g]·x_t + w_hh[g]·h
        float z = bias;
        const float* xc = x_s[t & 1];
        #pragma unroll
        for (int k = 0; k < Dd; ++k) z += wih[k] * xc[k];
        #pragma unroll
        for (int k = 0; k < Hh; ++k) z += whh[k] * h_s[k];

        // activation: tanh for wave 2, sigmoid otherwise (overflow-safe)
        float act;
        if (wave == 2) {
            float e = __expf(2.0f * fabsf(z));
            float r = 1.0f - 2.0f / (e + 1.0f);
            act = (z < 0.0f) ? -r : r;
        } else {
            act = 1.0f / (1.0f + __expf(-z));
        }

        if (wave < 3) gate_s[tid] = act;          // publish i, f, g
        if (tid < Dd) x_s[(t + 1) & 1][tid] = xn; // publish next x
        __syncthreads();                          // barrier A

        if (wave == 3) {                          // o-wave owns c/h update
            float i_ = gate_s[lane];
            float f_ = gate_s[Hh + lane];
            float g_ = gate_s[2 * Hh + lane];
            c = f_ * c + i_ * g_;
            float e = __expf(2.0f * fabsf(c));
            float r = 1.0f - 2.0f / (e + 1.0f);
            float th = (c < 0.0f) ? -r : r;
            h_s[lane] = act * th;                 // act == o
        }
        __syncthreads();                          // barrier B
    }

    // --- epilogue: out[b] = h_T @ fc_w^T + fc_b ---
    if (tid < OUTN) {
        float acc = fc_b[tid];
        #pragma unroll
        for (int j = 0; j < Hh; ++j) acc += fc_w[tid * Hh + j] * h_s[j];
        out[b * OUTN + tid] = acc;
    }
}

extern "C" void kernel_launch(void* const* d_in, const int* in_sizes, int n_in,
                              void* d_out, int out_size, void* d_ws, size_t ws_size,
                              hipStream_t stream) {
    const float* x    = (const float*)d_in[0];
    const float* w_ih = (const float*)d_in[1];
    const float* w_hh = (const float*)d_in[2];
    const float* b_ih = (const float*)d_in[3];
    const float* b_hh = (const float*)d_in[4];
    const float* fc_w = (const float*)d_in[5];
    const float* fc_b = (const float*)d_in[6];
    float* out = (float*)d_out;

    lstm_fused_kernel<<<Bb, 256, 0, stream>>>(x, w_ih, w_hh, b_ih, b_hh,
                                              fc_w, fc_b, out);
}

// Round 2
// 1427.033 us; speedup vs baseline: 1.3132x; 1.3132x over previous
//
#include <hip/hip_runtime.h>
#include <math.h>

// LSTM B=256, T=2048, D=H=64, OUT=8, fp32.
// One block per batch row (grid 256 = CU count), 256 threads = 4 waves.
// thread tid owns gate row tid (wave0=i, wave1=f, wave2=g, wave3=o).
// KEY: weights pinned in VGPRs via opaque asm (defeats LLVM's global-load
// rematerialization that made round-1 L2-BW-bound: VGPR=84 < 128 needed).
// c/h update replicated in all 4 waves (identical values -> benign LDS race)
// => ONE barrier per timestep. x staged in double-buffered 16KB LDS chunks
// with register prefetch issued 62 steps ahead.

#define Hh 64
#define Tt 2048
#define Dd 64
#define Bb 256
#define OUTN 8
#define CHUNK 64
#define NCHUNK (Tt / CHUNK)

typedef float floatx4 __attribute__((ext_vector_type(4)));

__global__ __launch_bounds__(256, 1)
void lstm_fused_kernel(const float* __restrict__ x,
                       const float* __restrict__ w_ih,
                       const float* __restrict__ w_hh,
                       const float* __restrict__ b_ih,
                       const float* __restrict__ b_hh,
                       const float* __restrict__ fc_w,
                       const float* __restrict__ fc_b,
                       float* __restrict__ out)
{
    __shared__ __align__(16) float xch[2][CHUNK * Dd];  // 2 x 16 KB
    __shared__ __align__(16) float h_s[Hh];
    __shared__ float gate_s[2][4 * Hh];

    const int tid  = threadIdx.x;   // gate index 0..255
    const int b    = blockIdx.x;    // batch row
    const int wave = tid >> 6;      // 0:i 1:f 2:g 3:o
    const int lane = tid & 63;      // hidden index for the c/h update

    const float* xb = x + (size_t)b * Tt * Dd;

    // ---- weights -> registers, pinned via opaque asm ----
    floatx4 wih4[16], whh4[16];
    {
        const floatx4* p = (const floatx4*)(w_ih + (size_t)tid * Dd);
        const floatx4* q = (const floatx4*)(w_hh + (size_t)tid * Hh);
        #pragma unroll
        for (int k = 0; k < 16; ++k) { wih4[k] = p[k]; whh4[k] = q[k]; }
    }
    #pragma unroll
    for (int k = 0; k < 16; ++k) {
        asm volatile("" : "+v"(wih4[k]));   // values now opaque: cannot be
        asm volatile("" : "+v"(whh4[k]));   // rematerialized or re-loaded
    }
    const float bias = b_ih[tid] + b_hh[tid];

    // ---- preload chunk 0, zero h ----
    {
        const floatx4* src = (const floatx4*)xb;
        floatx4* dst = (floatx4*)&xch[0][0];
        #pragma unroll
        for (int j = 0; j < 4; ++j) dst[tid + j * 256] = src[tid + j * 256];
    }
    if (tid < Hh) h_s[tid] = 0.0f;
    float c = 0.0f;                 // replicated: lane j of EVERY wave holds c[j]
    __syncthreads();

    for (int cc = 0; cc < NCHUNK; ++cc) {
        // prefetch next chunk into registers (62 steps of latency cover)
        floatx4 pf0, pf1, pf2, pf3;
        if (cc + 1 < NCHUNK) {
            const floatx4* src = (const floatx4*)(xb + (size_t)(cc + 1) * CHUNK * Dd);
            pf0 = src[tid];       pf1 = src[tid + 256];
            pf2 = src[tid + 512]; pf3 = src[tid + 768];
        }
        const float* xcbuf = &xch[cc & 1][0];

        #pragma unroll 2
        for (int s = 0; s < CHUNK; ++s) {
            // z = bias + w_ih[g].x_t + w_hh[g].h   (weights in VGPRs,
            // x/h broadcast from LDS as b128 reads; 4 fma chains)
            const floatx4* xv4 = (const floatx4*)(xcbuf + s * Dd);
            const floatx4* hv4 = (const floatx4*)h_s;
            floatx4 acc = {0.f, 0.f, 0.f, 0.f};
            #pragma unroll
            for (int k = 0; k < 16; ++k) acc += wih4[k] * xv4[k];
            #pragma unroll
            for (int k = 0; k < 16; ++k) acc += whh4[k] * hv4[k];
            float z = bias + ((acc.x + acc.y) + (acc.z + acc.w));

            float a;
            if (wave == 2) {                       // tanh (overflow-safe)
                float e = __expf(2.0f * fabsf(z));
                float r = 1.0f - 2.0f / (e + 1.0f);
                a = (z < 0.0f) ? -r : r;
            } else {                               // sigmoid
                a = 1.0f / (1.0f + __expf(-z));
            }
            gate_s[s & 1][tid] = a;                // double-buffered gates

            if (cc + 1 < NCHUNK && s == CHUNK - 2) {   // publish next x chunk
                floatx4* dst = (floatx4*)&xch[(cc + 1) & 1][0];
                dst[tid] = pf0;       dst[tid + 256] = pf1;
                dst[tid + 512] = pf2; dst[tid + 768] = pf3;
            }
            __syncthreads();                       // the ONE barrier per step

            // replicated c/h update (all 4 waves, identical values)
            const float* g0 = gate_s[s & 1];
            float i_ = g0[lane];
            float f_ = g0[64 + lane];
            float gg = g0[128 + lane];
            float o_ = g0[192 + lane];
            c = f_ * c + i_ * gg;
            float e  = __expf(2.0f * fabsf(c));
            float r  = 1.0f - 2.0f / (e + 1.0f);
            float th = (c < 0.0f) ? -r : r;
            h_s[lane] = o_ * th;   // benign race: all waves write same bytes
        }
    }
    __syncthreads();

    // ---- epilogue: out[b] = h_T @ fc_w^T + fc_b ----
    if (tid < OUTN) {
        float acc = fc_b[tid];
        #pragma unroll
        for (int j = 0; j < Hh; ++j) acc += fc_w[tid * Hh + j] * h_s[j];
        out[b * OUTN + tid] = acc;
    }
}

extern "C" void kernel_launch(void* const* d_in, const int* in_sizes, int n_in,
                              void* d_out, int out_size, void* d_ws, size_t ws_size,
                              hipStream_t stream) {
    const float* x    = (const float*)d_in[0];
    const float* w_ih = (const float*)d_in[1];
    const float* w_hh = (const float*)d_in[2];
    const float* b_ih = (const float*)d_in[3];
    const float* b_hh = (const float*)d_in[4];
    const float* fc_w = (const float*)d_in[5];
    const float* fc_b = (const float*)d_in[6];
    float* out = (float*)d_out;

    lstm_fused_kernel<<<Bb, 256, 0, stream>>>(x, w_ih, w_hh, b_ih, b_hh,
                                              fc_w, fc_b, out);
}